// Round 1
// baseline (3214.162 us; speedup 1.0000x reference)
//
#include <hip/hip_runtime.h>
#include <hip/hip_bf16.h>

using bf16 = __hip_bfloat16;

// Sizes (fixed by the problem)
// B=8 S=32 N=64 F_NODE=32 TRI=2016 DIN=2048 H=4 DOUT=256 R=1024 OUT=2016
// G = B*S = 256 graphs

__device__ __forceinline__ float bfu2f(unsigned int u16) {
  return __uint_as_float(u16 << 16);
}
__device__ __forceinline__ void unp2(unsigned int u, float& a, float& b) {
  a = __uint_as_float(u << 16);
  b = __uint_as_float(u & 0xffff0000u);
}

// ---------------------------------------------------------------------------
// Generic tiled fp32 GEMM.  C[m,n] = bias[n] + sum_k A[m,k]*B(k,n)
// BT=true : B is [N,K] row-major (dot rows of A with rows of B)   (A * B^T)
// BT=false: B is [K,N] row-major                                   (A * B)
// Tiles: BM=64, BN=64, BK=32; 256 threads, 4x4 outputs each.
// Requires M%64==0, N%64==0, K%32==0.
// ---------------------------------------------------------------------------
template <bool BT>
__global__ __launch_bounds__(256) void gemm_k(const float* __restrict__ A,
                                              const float* __restrict__ Bm,
                                              const float* __restrict__ bias,
                                              float* __restrict__ C,
                                              int K, int lda, int ldb, int ldc) {
  __shared__ float As[32][68];
  __shared__ float Bs[32][68];
  const int bm = blockIdx.y * 64, bn = blockIdx.x * 64;
  const int tid = threadIdx.x;
  const int tx = tid & 15, ty = tid >> 4;
  float acc[4][4] = {};
  for (int k0 = 0; k0 < K; k0 += 32) {
    __syncthreads();
    for (int idx = tid; idx < 2048; idx += 256) {
      int m = idx >> 5, kk = idx & 31;
      As[kk][m] = A[(bm + m) * lda + (k0 + kk)];
    }
    if (BT) {
      for (int idx = tid; idx < 2048; idx += 256) {
        int n = idx >> 5, kk = idx & 31;
        Bs[kk][n] = Bm[(bn + n) * ldb + (k0 + kk)];
      }
    } else {
      for (int idx = tid; idx < 2048; idx += 256) {
        int kk = idx >> 6, n = idx & 63;
        Bs[kk][n] = Bm[(k0 + kk) * ldb + (bn + n)];
      }
    }
    __syncthreads();
#pragma unroll
    for (int kk = 0; kk < 32; ++kk) {
      float a0 = As[kk][ty * 4 + 0], a1 = As[kk][ty * 4 + 1];
      float a2 = As[kk][ty * 4 + 2], a3 = As[kk][ty * 4 + 3];
      float b0 = Bs[kk][tx * 4 + 0], b1 = Bs[kk][tx * 4 + 1];
      float b2 = Bs[kk][tx * 4 + 2], b3 = Bs[kk][tx * 4 + 3];
      acc[0][0] += a0 * b0; acc[0][1] += a0 * b1; acc[0][2] += a0 * b2; acc[0][3] += a0 * b3;
      acc[1][0] += a1 * b0; acc[1][1] += a1 * b1; acc[1][2] += a1 * b2; acc[1][3] += a1 * b3;
      acc[2][0] += a2 * b0; acc[2][1] += a2 * b1; acc[2][2] += a2 * b2; acc[2][3] += a2 * b3;
      acc[3][0] += a3 * b0; acc[3][1] += a3 * b1; acc[3][2] += a3 * b2; acc[3][3] += a3 * b3;
    }
  }
#pragma unroll
  for (int i2 = 0; i2 < 4; ++i2)
#pragma unroll
    for (int j2 = 0; j2 < 4; ++j2) {
      int m = bm + ty * 4 + i2, n = bn + tx * 4 + j2;
      float v = acc[i2][j2] + (bias ? bias[n] : 0.0f);
      C[m * ldc + n] = v;
    }
}

// ---------------------------------------------------------------------------
// h[g,n,c] = he[g,c] + sum_f x_node[g,n,f] * Wg[f,c]   -> stored bf16
// grid: (4 c-quarters, 256 g), 256 threads (one column each)
// ---------------------------------------------------------------------------
__global__ __launch_bounds__(256) void node_h_k(const float* __restrict__ xn,
                                                const float* __restrict__ Wg,
                                                const float* __restrict__ he,
                                                bf16* __restrict__ hbuf) {
  __shared__ float xns[64][32];
  __shared__ float wgs[32][256];
  const int cq = blockIdx.x, g = blockIdx.y;
  const int tid = threadIdx.x;
  for (int idx = tid; idx < 2048; idx += 256) xns[idx >> 5][idx & 31] = xn[g * 2048 + idx];
  for (int r = 0; r < 32; ++r) wgs[r][tid] = Wg[r * 1024 + cq * 256 + tid];
  __syncthreads();
  const float hev = he[g * 1024 + cq * 256 + tid];
  for (int n0 = 0; n0 < 64; n0 += 8) {
    float acc[8];
#pragma unroll
    for (int nn = 0; nn < 8; ++nn) acc[nn] = hev;
    for (int f = 0; f < 32; ++f) {
      float w = wgs[f][tid];
#pragma unroll
      for (int nn = 0; nn < 8; ++nn) acc[nn] += xns[n0 + nn][f] * w;
    }
#pragma unroll
    for (int nn = 0; nn < 8; ++nn)
      hbuf[(size_t)(g * 64 + n0 + nn) * 1024 + cq * 256 + tid] = __float2bfloat16(acc[nn]);
  }
}

// ---------------------------------------------------------------------------
// a_s[row,hd] = sum_e h[row, hd*256+e] * att_src[hd,e]; same for a_d.
// One wave per row (g*64+n); 4 waves per block.
// ---------------------------------------------------------------------------
__global__ __launch_bounds__(256) void as_ad_k(const bf16* __restrict__ hbuf,
                                               const float* __restrict__ att_s,
                                               const float* __restrict__ att_d,
                                               float* __restrict__ as_o,
                                               float* __restrict__ ad_o) {
  const int tid = threadIdx.x;
  const int lane = tid & 63, wv = tid >> 6;
  const int row = blockIdx.x * 4 + wv;
  const int hd = lane >> 4;
  const int e0 = (lane & 15) * 16;
  float as_r[16], ad_r[16];
#pragma unroll
  for (int q = 0; q < 4; ++q) {
    float4 v = *(const float4*)(att_s + hd * 256 + e0 + q * 4);
    as_r[q * 4 + 0] = v.x; as_r[q * 4 + 1] = v.y; as_r[q * 4 + 2] = v.z; as_r[q * 4 + 3] = v.w;
    float4 w = *(const float4*)(att_d + hd * 256 + e0 + q * 4);
    ad_r[q * 4 + 0] = w.x; ad_r[q * 4 + 1] = w.y; ad_r[q * 4 + 2] = w.z; ad_r[q * 4 + 3] = w.w;
  }
  const uint4* hp = (const uint4*)(hbuf + (size_t)row * 1024 + lane * 16);
  uint4 p0 = hp[0], p1 = hp[1];
  float hv[16];
  unp2(p0.x, hv[0], hv[1]);  unp2(p0.y, hv[2], hv[3]);
  unp2(p0.z, hv[4], hv[5]);  unp2(p0.w, hv[6], hv[7]);
  unp2(p1.x, hv[8], hv[9]);  unp2(p1.y, hv[10], hv[11]);
  unp2(p1.z, hv[12], hv[13]); unp2(p1.w, hv[14], hv[15]);
  float ps = 0.f, pd = 0.f;
#pragma unroll
  for (int i = 0; i < 16; ++i) { ps += as_r[i] * hv[i]; pd += ad_r[i] * hv[i]; }
#pragma unroll
  for (int m = 1; m < 16; m <<= 1) { ps += __shfl_xor(ps, m); pd += __shfl_xor(pd, m); }
  if ((lane & 15) == 0) { as_o[row * 4 + hd] = ps; ad_o[row * 4 + hd] = pd; }
}

// ---------------------------------------------------------------------------
// Per graph g: softmax over sources + head-mean aggregation + bias + relu.
// Writes seq[g, i*256+e].
// ---------------------------------------------------------------------------
__global__ __launch_bounds__(256) void attn_agg_k(const bf16* __restrict__ hbuf,
                                                  const float* __restrict__ as_i,
                                                  const float* __restrict__ ad_i,
                                                  const float* __restrict__ bgat,
                                                  float* __restrict__ seq) {
  __shared__ float ass[256], ads[256], bgs[256];
  __shared__ float alpha[4][64][64];   // [hd][j][i]
  __shared__ float hq[64][260];        // one head-quarter of h, fp32
  const int g = blockIdx.x, tid = threadIdx.x;
  ass[tid] = as_i[g * 256 + tid];
  ads[tid] = ad_i[g * 256 + tid];
  bgs[tid] = bgat[tid];
  __syncthreads();
  {
    const int hd = tid >> 6, i = tid & 63;
    const float ad = ads[i * 4 + hd];
    float m = -1e30f;
    for (int j = 0; j < 64; ++j) {
      float s = ad + ass[j * 4 + hd];
      s = s > 0.0f ? s : 0.2f * s;
      m = fmaxf(m, s);
    }
    float sum = 0.0f;
    for (int j = 0; j < 64; ++j) {
      float s = ad + ass[j * 4 + hd];
      s = s > 0.0f ? s : 0.2f * s;
      sum += __expf(s - m);
    }
    const float inv = 1.0f / sum;
    for (int j = 0; j < 64; ++j) {
      float s = ad + ass[j * 4 + hd];
      s = s > 0.0f ? s : 0.2f * s;
      alpha[hd][j][i] = __expf(s - m) * inv;
    }
  }
  const int i = tid & 63, eq = tid >> 6;
  float acc[64] = {};
  for (int hd = 0; hd < 4; ++hd) {
    __syncthreads();
    for (int idx = tid; idx < 2048; idx += 256) {
      int j = idx >> 5, ch = idx & 31;
      uint4 p = *(const uint4*)(hbuf + (size_t)(g * 64 + j) * 1024 + hd * 256 + ch * 8);
      float f0, f1, f2, f3, f4, f5, f6, f7;
      unp2(p.x, f0, f1); unp2(p.y, f2, f3); unp2(p.z, f4, f5); unp2(p.w, f6, f7);
      *(float4*)&hq[j][ch * 8] = make_float4(f0, f1, f2, f3);
      *(float4*)&hq[j][ch * 8 + 4] = make_float4(f4, f5, f6, f7);
    }
    __syncthreads();
    for (int j = 0; j < 64; ++j) {
      const float a = alpha[hd][j][i];
      const float* hr = &hq[j][eq * 64];
#pragma unroll
      for (int q = 0; q < 16; ++q) {
        float4 hv = *(const float4*)(hr + q * 4);
        acc[q * 4 + 0] += a * hv.x; acc[q * 4 + 1] += a * hv.y;
        acc[q * 4 + 2] += a * hv.z; acc[q * 4 + 3] += a * hv.w;
      }
    }
  }
  float* op = seq + (size_t)g * 16384 + i * 256 + eq * 64;
#pragma unroll
  for (int q = 0; q < 16; ++q) {
    float4 v;
    v.x = fmaxf(bgs[eq * 64 + q * 4 + 0] + 0.25f * acc[q * 4 + 0], 0.0f);
    v.y = fmaxf(bgs[eq * 64 + q * 4 + 1] + 0.25f * acc[q * 4 + 1], 0.0f);
    v.z = fmaxf(bgs[eq * 64 + q * 4 + 2] + 0.25f * acc[q * 4 + 2], 0.0f);
    v.w = fmaxf(bgs[eq * 64 + q * 4 + 3] + 0.25f * acc[q * 4 + 3], 0.0f);
    *(float4*)(op + q * 4) = v;
  }
}

// ---------------------------------------------------------------------------
// One GRU time step: h' = GRU(h, gi[:,s,:]) using gh = h @ Whh^T + bhh.
// grid 128 blocks, block owns 8 output j's; thread = (j_local, b, kquarter).
// Writes y[(b*32+s)*1024 + j]; reads h from y[(b*32+s-1)...] (zeros if first).
// ---------------------------------------------------------------------------
__global__ __launch_bounds__(256) void gru_step_k(const float* __restrict__ X,
                                                  const float* __restrict__ Whh,
                                                  const float* __restrict__ bhh,
                                                  float* __restrict__ y,
                                                  int s, int first) {
  __shared__ float hs[8][1028];
  __shared__ float ws[24][516];
  const int tid = threadIdx.x;
  for (int idx = tid; idx < 2048; idx += 256) {
    int b = idx >> 8, kf = idx & 255;
    float4 v = make_float4(0.f, 0.f, 0.f, 0.f);
    if (!first) v = *(const float4*)(y + (size_t)(b * 32 + (s - 1)) * 1024 + kf * 4);
    *(float4*)&hs[b][kf * 4] = v;
  }
  const int j0 = blockIdx.x * 8;
  const int jl = tid >> 5, b = (tid >> 2) & 7, kq = tid & 3;
  float acc0 = 0.f, acc1 = 0.f, acc2 = 0.f;
  for (int c = 0; c < 2; ++c) {
    __syncthreads();
    for (int idx = tid; idx < 3072; idx += 256) {
      int row = idx >> 7, kf = idx & 127;
      int gg = row >> 3, jj = row & 7;
      float4 v = *(const float4*)(Whh + (size_t)(gg * 1024 + j0 + jj) * 1024 + c * 512 + kf * 4);
      *(float4*)&ws[row][kf * 4] = v;
    }
    __syncthreads();
#pragma unroll 8
    for (int i2 = 0; i2 < 32; ++i2) {
      int kf = i2 * 4 + kq;
      float4 hv = *(const float4*)&hs[b][c * 512 + kf * 4];
      float4 w0 = *(const float4*)&ws[jl][kf * 4];
      float4 w1 = *(const float4*)&ws[8 + jl][kf * 4];
      float4 w2 = *(const float4*)&ws[16 + jl][kf * 4];
      acc0 += hv.x * w0.x + hv.y * w0.y + hv.z * w0.z + hv.w * w0.w;
      acc1 += hv.x * w1.x + hv.y * w1.y + hv.z * w1.z + hv.w * w1.w;
      acc2 += hv.x * w2.x + hv.y * w2.y + hv.z * w2.z + hv.w * w2.w;
    }
  }
  acc0 += __shfl_xor(acc0, 1); acc0 += __shfl_xor(acc0, 2);
  acc1 += __shfl_xor(acc1, 1); acc1 += __shfl_xor(acc1, 2);
  acc2 += __shfl_xor(acc2, 1); acc2 += __shfl_xor(acc2, 2);
  if (kq == 0) {
    const int j = j0 + jl;
    const float* gi = X + (size_t)(b * 32 + s) * 3072;
    float ir = gi[j], iz = gi[1024 + j], in_ = gi[2048 + j];
    float hr = acc0 + bhh[j], hz = acc1 + bhh[1024 + j], hn = acc2 + bhh[2048 + j];
    float r = 1.0f / (1.0f + __expf(-(ir + hr)));
    float z = 1.0f / (1.0f + __expf(-(iz + hz)));
    float n = tanhf(in_ + r * hn);
    float hp = hs[b][j];
    y[(size_t)(b * 32 + s) * 1024 + j] = (1.0f - z) * n + z * hp;
  }
}

// ---------------------------------------------------------------------------
// out[b,o] = b_fc[o] + sum_k y1[b,31,k] * Wfc[k,o]
// 32 blocks; thread = (o_local 0..63, kquarter 0..3)
// ---------------------------------------------------------------------------
__global__ __launch_bounds__(256) void fc_k(const float* __restrict__ y1,
                                            const float* __restrict__ Wfc,
                                            const float* __restrict__ bfc,
                                            float* __restrict__ out) {
  __shared__ float As[8][1024];
  const int tid = threadIdx.x;
  for (int idx = tid; idx < 8192; idx += 256) {
    int b = idx >> 10, k = idx & 1023;
    As[b][k] = y1[(size_t)(b * 32 + 31) * 1024 + k];
  }
  __syncthreads();
  const int ol = tid >> 2, kq = tid & 3;
  const int o = blockIdx.x * 64 + ol;
  float acc[8] = {};
  if (o < 2016) {
    for (int i2 = 0; i2 < 256; ++i2) {
      int k = i2 * 4 + kq;
      float w = Wfc[(size_t)k * 2016 + o];
#pragma unroll
      for (int b = 0; b < 8; ++b) acc[b] += As[b][k] * w;
    }
  }
#pragma unroll
  for (int b = 0; b < 8; ++b) {
    acc[b] += __shfl_xor(acc[b], 1);
    acc[b] += __shfl_xor(acc[b], 2);
  }
  if (kq == 0 && o < 2016) {
#pragma unroll
    for (int b = 0; b < 8; ++b) out[b * 2016 + o] = acc[b] + bfc[o];
  }
}

// ---------------------------------------------------------------------------
extern "C" void kernel_launch(void* const* d_in, const int* in_sizes, int n_in,
                              void* d_out, int out_size, void* d_ws, size_t ws_size,
                              hipStream_t stream) {
  (void)in_sizes; (void)n_in; (void)out_size; (void)ws_size;
  const float* x_node = (const float*)d_in[0];
  const float* x_edge = (const float*)d_in[1];
  // d_in[2] = edge_index: complete graph + self loops -> dense; unused.
  const float* W_gat = (const float*)d_in[3];
  const float* att_s = (const float*)d_in[4];
  const float* att_d = (const float*)d_in[5];
  const float* b_gat = (const float*)d_in[6];
  const float* W_ih0 = (const float*)d_in[7];
  const float* W_hh0 = (const float*)d_in[8];
  const float* b_ih0 = (const float*)d_in[9];
  const float* b_hh0 = (const float*)d_in[10];
  const float* W_ih1 = (const float*)d_in[11];
  const float* W_hh1 = (const float*)d_in[12];
  const float* b_ih1 = (const float*)d_in[13];
  const float* b_hh1 = (const float*)d_in[14];
  const float* W_fc  = (const float*)d_in[15];
  const float* b_fc  = (const float*)d_in[16];

  char* ws = (char*)d_ws;
  size_t off = 0;
  float* he  = (float*)(ws + off); off += 256u * 1024 * 4;          // 1 MB
  float* a_s = (float*)(ws + off); off += 256u * 64 * 4 * 4;        // 256 KB
  float* a_d = (float*)(ws + off); off += 256u * 64 * 4 * 4;        // 256 KB
  bf16*  hb  = (bf16*)(ws + off);  off += 256u * 64 * 1024 * 2;     // 32 MB
  float* seq = (float*)(ws + off); off += 256u * 16384 * 4;         // 16 MB
  float* X0  = (float*)(ws + off); off += 256u * 3072 * 4;          // 3 MB
  float* y0  = (float*)(ws + off); off += 256u * 1024 * 4;          // 1 MB
  float* X1  = (float*)(ws + off); off += 256u * 3072 * 4;          // 3 MB
  float* y1  = (float*)(ws + off); off += 256u * 1024 * 4;          // 1 MB  (total ~57.5 MB)

  // 1) he = x_edge @ W_gat[32:, :]          (M=256, N=1024, K=2016)
  gemm_k<false><<<dim3(16, 4), 256, 0, stream>>>(x_edge, W_gat + 32 * 1024, nullptr, he,
                                                 2016, 2016, 1024, 1024);
  // 2) h = node-proj + he (bf16)
  node_h_k<<<dim3(4, 256), 256, 0, stream>>>(x_node, W_gat, he, hb);
  // 3) attention logits
  as_ad_k<<<4096, 256, 0, stream>>>(hb, att_s, att_d, a_s, a_d);
  // 4) softmax + aggregation + relu -> seq [256, 16384]
  attn_agg_k<<<256, 256, 0, stream>>>(hb, a_s, a_d, b_gat, seq);
  // 5) X0 = seq @ W_ih0^T + b_ih0          (M=256, N=3072, K=16384)
  gemm_k<true><<<dim3(48, 4), 256, 0, stream>>>(seq, W_ih0, b_ih0, X0,
                                                16384, 16384, 16384, 3072);
  // 6) GRU layer 0 scan
  for (int s = 0; s < 32; ++s)
    gru_step_k<<<128, 256, 0, stream>>>(X0, W_hh0, b_hh0, y0, s, s == 0 ? 1 : 0);
  // 7) X1 = y0 @ W_ih1^T + b_ih1           (M=256, N=3072, K=1024)
  gemm_k<true><<<dim3(48, 4), 256, 0, stream>>>(y0, W_ih1, b_ih1, X1,
                                                1024, 1024, 1024, 3072);
  // 8) GRU layer 1 scan
  for (int s = 0; s < 32; ++s)
    gru_step_k<<<128, 256, 0, stream>>>(X1, W_hh1, b_hh1, y1, s, s == 0 ? 1 : 0);
  // 9) out = y1[:, 31] @ W_fc + b_fc
  fc_k<<<32, 256, 0, stream>>>(y1, W_fc, b_fc, (float*)d_out);
}

// Round 2
// 1114.253 us; speedup vs baseline: 2.8846x; 2.8846x over previous
//
#include <hip/hip_runtime.h>
#include <hip/hip_bf16.h>

using bf16 = __hip_bfloat16;
typedef __bf16 bf16x8 __attribute__((ext_vector_type(8)));
typedef float f32x4 __attribute__((ext_vector_type(4)));

// Sizes (fixed): B=8 S=32 N=64 F_NODE=32 TRI=2016 DIN=2048 H=4 DOUT=256 R=1024
// OUT=2016, G=B*S=256 graphs

__device__ __forceinline__ void unp2(unsigned int u, float& a, float& b) {
  a = __uint_as_float(u << 16);
  b = __uint_as_float(u & 0xffff0000u);
}

__device__ __forceinline__ bf16x8 cvt8(float4 a, float4 b) {
  bf16x8 r;
  r[0] = (__bf16)a.x; r[1] = (__bf16)a.y; r[2] = (__bf16)a.z; r[3] = (__bf16)a.w;
  r[4] = (__bf16)b.x; r[5] = (__bf16)b.y; r[6] = (__bf16)b.z; r[7] = (__bf16)b.w;
  return r;
}

// ---------------------------------------------------------------------------
// MFMA bf16 GEMM with split-K partials.
// Cp[z][m][n] = sum_{k in chunk z} A[m,k] * B'(k,n)
// A: [M,K] fp32 row-major.  BT=true: Bm is [N,K] (A@B^T).  BT=false: Bm is [K,N].
// Tile 128x128, BK=32, 256 threads = 4 waves, each wave 64x64 (4x4 16x16x32 frags).
// fp32 inputs converted to bf16 during LDS staging; fp32 accumulate.
// Requires M%128==0, N%128==0, K%32==0.
// ---------------------------------------------------------------------------
template <bool BT>
__global__ __launch_bounds__(256) void mfma_gemm_k(const float* __restrict__ A,
                                                   const float* __restrict__ Bm,
                                                   float* __restrict__ Cp,
                                                   int M, int N, int K,
                                                   int lda, int ldb, int ksper) {
  __shared__ __bf16 As[128][40];  // 80B row stride: 16B-aligned, 2-way bank alias
  __shared__ __bf16 Bs[128][40];
  const int tid = threadIdx.x;
  const int bm = blockIdx.y * 128, bn = blockIdx.x * 128;
  const int lane = tid & 63, wv = tid >> 6;
  const int wr = wv >> 1, wc = wv & 1;
  const int lr = lane & 15, kh = lane >> 4;
  f32x4 acc[4][4] = {};
  const int kstot = K >> 5;
  int ks0 = blockIdx.z * ksper;
  int ks1 = ks0 + ksper; if (ks1 > kstot) ks1 = kstot;
  for (int ks = ks0; ks < ks1; ++ks) {
    const int k0 = ks << 5;
    __syncthreads();
    {  // stage A: thread t -> row t>>1, 16 floats at half (t&1)
      const int row = tid >> 1, half = tid & 1;
      const float* ap = A + (size_t)(bm + row) * lda + k0 + half * 16;
      float4 f0 = ((const float4*)ap)[0], f1 = ((const float4*)ap)[1];
      float4 f2 = ((const float4*)ap)[2], f3 = ((const float4*)ap)[3];
      *(bf16x8*)&As[row][half * 16] = cvt8(f0, f1);
      *(bf16x8*)&As[row][half * 16 + 8] = cvt8(f2, f3);
    }
    if (BT) {  // stage B rows (already k-contiguous)
      const int row = tid >> 1, half = tid & 1;
      const float* bp = Bm + (size_t)(bn + row) * ldb + k0 + half * 16;
      float4 f0 = ((const float4*)bp)[0], f1 = ((const float4*)bp)[1];
      float4 f2 = ((const float4*)bp)[2], f3 = ((const float4*)bp)[3];
      *(bf16x8*)&Bs[row][half * 16] = cvt8(f0, f1);
      *(bf16x8*)&Bs[row][half * 16 + 8] = cvt8(f2, f3);
    } else {   // B is [K,N]: coalesced load along n, transpose into Bs[n][k]
      const int kk = tid >> 3, ng = tid & 7;
      const float* bp = Bm + (size_t)(k0 + kk) * ldb + bn + ng * 16;
      float4 f[4];
#pragma unroll
      for (int q = 0; q < 4; ++q) f[q] = ((const float4*)bp)[q];
#pragma unroll
      for (int q = 0; q < 4; ++q) {
        Bs[ng * 16 + q * 4 + 0][kk] = (__bf16)f[q].x;
        Bs[ng * 16 + q * 4 + 1][kk] = (__bf16)f[q].y;
        Bs[ng * 16 + q * 4 + 2][kk] = (__bf16)f[q].z;
        Bs[ng * 16 + q * 4 + 3][kk] = (__bf16)f[q].w;
      }
    }
    __syncthreads();
    bf16x8 af[4], bfv[4];
#pragma unroll
    for (int mi = 0; mi < 4; ++mi)
      af[mi] = *(const bf16x8*)&As[wr * 64 + mi * 16 + lr][kh * 8];
#pragma unroll
    for (int ni = 0; ni < 4; ++ni)
      bfv[ni] = *(const bf16x8*)&Bs[wc * 64 + ni * 16 + lr][kh * 8];
#pragma unroll
    for (int mi = 0; mi < 4; ++mi)
#pragma unroll
      for (int ni = 0; ni < 4; ++ni)
        acc[mi][ni] = __builtin_amdgcn_mfma_f32_16x16x32_bf16(af[mi], bfv[ni],
                                                              acc[mi][ni], 0, 0, 0);
  }
  float* cp = Cp + (size_t)blockIdx.z * M * N;
#pragma unroll
  for (int mi = 0; mi < 4; ++mi) {
#pragma unroll
    for (int ni = 0; ni < 4; ++ni) {
      const int row = bm + wr * 64 + mi * 16 + kh * 4;  // C/D: col=lane&15, row=kh*4+j
      const int col = bn + wc * 64 + ni * 16 + lr;
#pragma unroll
      for (int j = 0; j < 4; ++j)
        cp[(size_t)(row + j) * N + col] = acc[mi][ni][j];
    }
  }
}

// C[i] = bias[i%N] + sum_sk Cp[sk][i], float4-vectorized
__global__ __launch_bounds__(256) void reduce_k(const float* __restrict__ Cp,
                                                const float* __restrict__ bias,
                                                float* __restrict__ C,
                                                int MN, int N, int nsk) {
  int i = (blockIdx.x * 256 + threadIdx.x) * 4;
  if (i >= MN) return;
  float4 s = make_float4(0.f, 0.f, 0.f, 0.f);
  if (bias) s = *(const float4*)&bias[i % N];
  for (int sk = 0; sk < nsk; ++sk) {
    float4 p = *(const float4*)&Cp[(size_t)sk * MN + i];
    s.x += p.x; s.y += p.y; s.z += p.z; s.w += p.w;
  }
  *(float4*)&C[i] = s;
}

// ---------------------------------------------------------------------------
// h[g,n,c] = he[g,c] + sum_f x_node[g,n,f] * Wg[f,c]   -> stored bf16
// ---------------------------------------------------------------------------
__global__ __launch_bounds__(256) void node_h_k(const float* __restrict__ xn,
                                                const float* __restrict__ Wg,
                                                const float* __restrict__ he,
                                                bf16* __restrict__ hbuf) {
  __shared__ float xns[64][32];
  __shared__ float wgs[32][256];
  const int cq = blockIdx.x, g = blockIdx.y;
  const int tid = threadIdx.x;
  for (int idx = tid; idx < 2048; idx += 256) xns[idx >> 5][idx & 31] = xn[g * 2048 + idx];
  for (int r = 0; r < 32; ++r) wgs[r][tid] = Wg[r * 1024 + cq * 256 + tid];
  __syncthreads();
  const float hev = he[g * 1024 + cq * 256 + tid];
  for (int n0 = 0; n0 < 64; n0 += 8) {
    float acc[8];
#pragma unroll
    for (int nn = 0; nn < 8; ++nn) acc[nn] = hev;
    for (int f = 0; f < 32; ++f) {
      float w = wgs[f][tid];
#pragma unroll
      for (int nn = 0; nn < 8; ++nn) acc[nn] += xns[n0 + nn][f] * w;
    }
#pragma unroll
    for (int nn = 0; nn < 8; ++nn)
      hbuf[(size_t)(g * 64 + n0 + nn) * 1024 + cq * 256 + tid] = __float2bfloat16(acc[nn]);
  }
}

// ---------------------------------------------------------------------------
// a_s[row,hd] = sum_e h[row, hd*256+e] * att_src[hd,e]; same for a_d.
// ---------------------------------------------------------------------------
__global__ __launch_bounds__(256) void as_ad_k(const bf16* __restrict__ hbuf,
                                               const float* __restrict__ att_s,
                                               const float* __restrict__ att_d,
                                               float* __restrict__ as_o,
                                               float* __restrict__ ad_o) {
  const int tid = threadIdx.x;
  const int lane = tid & 63, wv = tid >> 6;
  const int row = blockIdx.x * 4 + wv;
  const int hd = lane >> 4;
  const int e0 = (lane & 15) * 16;
  float as_r[16], ad_r[16];
#pragma unroll
  for (int q = 0; q < 4; ++q) {
    float4 v = *(const float4*)(att_s + hd * 256 + e0 + q * 4);
    as_r[q * 4 + 0] = v.x; as_r[q * 4 + 1] = v.y; as_r[q * 4 + 2] = v.z; as_r[q * 4 + 3] = v.w;
    float4 w = *(const float4*)(att_d + hd * 256 + e0 + q * 4);
    ad_r[q * 4 + 0] = w.x; ad_r[q * 4 + 1] = w.y; ad_r[q * 4 + 2] = w.z; ad_r[q * 4 + 3] = w.w;
  }
  const uint4* hp = (const uint4*)(hbuf + (size_t)row * 1024 + lane * 16);
  uint4 p0 = hp[0], p1 = hp[1];
  float hv[16];
  unp2(p0.x, hv[0], hv[1]);  unp2(p0.y, hv[2], hv[3]);
  unp2(p0.z, hv[4], hv[5]);  unp2(p0.w, hv[6], hv[7]);
  unp2(p1.x, hv[8], hv[9]);  unp2(p1.y, hv[10], hv[11]);
  unp2(p1.z, hv[12], hv[13]); unp2(p1.w, hv[14], hv[15]);
  float ps = 0.f, pd = 0.f;
#pragma unroll
  for (int i = 0; i < 16; ++i) { ps += as_r[i] * hv[i]; pd += ad_r[i] * hv[i]; }
#pragma unroll
  for (int m = 1; m < 16; m <<= 1) { ps += __shfl_xor(ps, m); pd += __shfl_xor(pd, m); }
  if ((lane & 15) == 0) { as_o[row * 4 + hd] = ps; ad_o[row * 4 + hd] = pd; }
}

// ---------------------------------------------------------------------------
// Per graph g: softmax over sources + head-mean aggregation + bias + relu.
// ---------------------------------------------------------------------------
__global__ __launch_bounds__(256) void attn_agg_k(const bf16* __restrict__ hbuf,
                                                  const float* __restrict__ as_i,
                                                  const float* __restrict__ ad_i,
                                                  const float* __restrict__ bgat,
                                                  float* __restrict__ seq) {
  __shared__ float ass[256], ads[256], bgs[256];
  __shared__ float alpha[4][64][64];   // [hd][j][i]
  __shared__ float hq[64][260];        // one head-quarter of h, fp32
  const int g = blockIdx.x, tid = threadIdx.x;
  ass[tid] = as_i[g * 256 + tid];
  ads[tid] = ad_i[g * 256 + tid];
  bgs[tid] = bgat[tid];
  __syncthreads();
  {
    const int hd = tid >> 6, i = tid & 63;
    const float ad = ads[i * 4 + hd];
    float m = -1e30f;
    for (int j = 0; j < 64; ++j) {
      float s = ad + ass[j * 4 + hd];
      s = s > 0.0f ? s : 0.2f * s;
      m = fmaxf(m, s);
    }
    float sum = 0.0f;
    for (int j = 0; j < 64; ++j) {
      float s = ad + ass[j * 4 + hd];
      s = s > 0.0f ? s : 0.2f * s;
      sum += __expf(s - m);
    }
    const float inv = 1.0f / sum;
    for (int j = 0; j < 64; ++j) {
      float s = ad + ass[j * 4 + hd];
      s = s > 0.0f ? s : 0.2f * s;
      alpha[hd][j][i] = __expf(s - m) * inv;
    }
  }
  const int i = tid & 63, eq = tid >> 6;
  float acc[64] = {};
  for (int hd = 0; hd < 4; ++hd) {
    __syncthreads();
    for (int idx = tid; idx < 2048; idx += 256) {
      int j = idx >> 5, ch = idx & 31;
      uint4 p = *(const uint4*)(hbuf + (size_t)(g * 64 + j) * 1024 + hd * 256 + ch * 8);
      float f0, f1, f2, f3, f4, f5, f6, f7;
      unp2(p.x, f0, f1); unp2(p.y, f2, f3); unp2(p.z, f4, f5); unp2(p.w, f6, f7);
      *(float4*)&hq[j][ch * 8] = make_float4(f0, f1, f2, f3);
      *(float4*)&hq[j][ch * 8 + 4] = make_float4(f4, f5, f6, f7);
    }
    __syncthreads();
    for (int j = 0; j < 64; ++j) {
      const float a = alpha[hd][j][i];
      const float* hr = &hq[j][eq * 64];
#pragma unroll
      for (int q = 0; q < 16; ++q) {
        float4 hv = *(const float4*)(hr + q * 4);
        acc[q * 4 + 0] += a * hv.x; acc[q * 4 + 1] += a * hv.y;
        acc[q * 4 + 2] += a * hv.z; acc[q * 4 + 3] += a * hv.w;
      }
    }
  }
  float* op = seq + (size_t)g * 16384 + i * 256 + eq * 64;
#pragma unroll
  for (int q = 0; q < 16; ++q) {
    float4 v;
    v.x = fmaxf(bgs[eq * 64 + q * 4 + 0] + 0.25f * acc[q * 4 + 0], 0.0f);
    v.y = fmaxf(bgs[eq * 64 + q * 4 + 1] + 0.25f * acc[q * 4 + 1], 0.0f);
    v.z = fmaxf(bgs[eq * 64 + q * 4 + 2] + 0.25f * acc[q * 4 + 2], 0.0f);
    v.w = fmaxf(bgs[eq * 64 + q * 4 + 3] + 0.25f * acc[q * 4 + 3], 0.0f);
    *(float4*)(op + q * 4) = v;
  }
}

// ---------------------------------------------------------------------------
// One GRU time step (see R0 comments).
// ---------------------------------------------------------------------------
__global__ __launch_bounds__(256) void gru_step_k(const float* __restrict__ X,
                                                  const float* __restrict__ Whh,
                                                  const float* __restrict__ bhh,
                                                  float* __restrict__ y,
                                                  int s, int first) {
  __shared__ float hs[8][1028];
  __shared__ float ws[24][516];
  const int tid = threadIdx.x;
  for (int idx = tid; idx < 2048; idx += 256) {
    int b = idx >> 8, kf = idx & 255;
    float4 v = make_float4(0.f, 0.f, 0.f, 0.f);
    if (!first) v = *(const float4*)(y + (size_t)(b * 32 + (s - 1)) * 1024 + kf * 4);
    *(float4*)&hs[b][kf * 4] = v;
  }
  const int j0 = blockIdx.x * 8;
  const int jl = tid >> 5, b = (tid >> 2) & 7, kq = tid & 3;
  float acc0 = 0.f, acc1 = 0.f, acc2 = 0.f;
  for (int c = 0; c < 2; ++c) {
    __syncthreads();
    for (int idx = tid; idx < 3072; idx += 256) {
      int row = idx >> 7, kf = idx & 127;
      int gg = row >> 3, jj = row & 7;
      float4 v = *(const float4*)(Whh + (size_t)(gg * 1024 + j0 + jj) * 1024 + c * 512 + kf * 4);
      *(float4*)&ws[row][kf * 4] = v;
    }
    __syncthreads();
#pragma unroll 8
    for (int i2 = 0; i2 < 32; ++i2) {
      int kf = i2 * 4 + kq;
      float4 hv = *(const float4*)&hs[b][c * 512 + kf * 4];
      float4 w0 = *(const float4*)&ws[jl][kf * 4];
      float4 w1 = *(const float4*)&ws[8 + jl][kf * 4];
      float4 w2 = *(const float4*)&ws[16 + jl][kf * 4];
      acc0 += hv.x * w0.x + hv.y * w0.y + hv.z * w0.z + hv.w * w0.w;
      acc1 += hv.x * w1.x + hv.y * w1.y + hv.z * w1.z + hv.w * w1.w;
      acc2 += hv.x * w2.x + hv.y * w2.y + hv.z * w2.z + hv.w * w2.w;
    }
  }
  acc0 += __shfl_xor(acc0, 1); acc0 += __shfl_xor(acc0, 2);
  acc1 += __shfl_xor(acc1, 1); acc1 += __shfl_xor(acc1, 2);
  acc2 += __shfl_xor(acc2, 1); acc2 += __shfl_xor(acc2, 2);
  if (kq == 0) {
    const int j = j0 + jl;
    const float* gi = X + (size_t)(b * 32 + s) * 3072;
    float ir = gi[j], iz = gi[1024 + j], in_ = gi[2048 + j];
    float hr = acc0 + bhh[j], hz = acc1 + bhh[1024 + j], hn = acc2 + bhh[2048 + j];
    float r = 1.0f / (1.0f + __expf(-(ir + hr)));
    float z = 1.0f / (1.0f + __expf(-(iz + hz)));
    float n = tanhf(in_ + r * hn);
    float hp = hs[b][j];
    y[(size_t)(b * 32 + s) * 1024 + j] = (1.0f - z) * n + z * hp;
  }
}

// ---------------------------------------------------------------------------
// out[b,o] = b_fc[o] + sum_k y1[b,31,k] * Wfc[k,o]
// ---------------------------------------------------------------------------
__global__ __launch_bounds__(256) void fc_k(const float* __restrict__ y1,
                                            const float* __restrict__ Wfc,
                                            const float* __restrict__ bfc,
                                            float* __restrict__ out) {
  __shared__ float As[8][1024];
  const int tid = threadIdx.x;
  for (int idx = tid; idx < 8192; idx += 256) {
    int b = idx >> 10, k = idx & 1023;
    As[b][k] = y1[(size_t)(b * 32 + 31) * 1024 + k];
  }
  __syncthreads();
  const int ol = tid >> 2, kq = tid & 3;
  const int o = blockIdx.x * 64 + ol;
  float acc[8] = {};
  if (o < 2016) {
    for (int i2 = 0; i2 < 256; ++i2) {
      int k = i2 * 4 + kq;
      float w = Wfc[(size_t)k * 2016 + o];
#pragma unroll
      for (int b = 0; b < 8; ++b) acc[b] += As[b][k] * w;
    }
  }
#pragma unroll
  for (int b = 0; b < 8; ++b) {
    acc[b] += __shfl_xor(acc[b], 1);
    acc[b] += __shfl_xor(acc[b], 2);
  }
  if (kq == 0 && o < 2016) {
#pragma unroll
    for (int b = 0; b < 8; ++b) out[b * 2016 + o] = acc[b] + bfc[o];
  }
}

// ---------------------------------------------------------------------------
extern "C" void kernel_launch(void* const* d_in, const int* in_sizes, int n_in,
                              void* d_out, int out_size, void* d_ws, size_t ws_size,
                              hipStream_t stream) {
  (void)in_sizes; (void)n_in; (void)out_size; (void)ws_size;
  const float* x_node = (const float*)d_in[0];
  const float* x_edge = (const float*)d_in[1];
  // d_in[2] = edge_index: complete graph + self loops -> dense; unused.
  const float* W_gat = (const float*)d_in[3];
  const float* att_s = (const float*)d_in[4];
  const float* att_d = (const float*)d_in[5];
  const float* b_gat = (const float*)d_in[6];
  const float* W_ih0 = (const float*)d_in[7];
  const float* W_hh0 = (const float*)d_in[8];
  const float* b_ih0 = (const float*)d_in[9];
  const float* b_hh0 = (const float*)d_in[10];
  const float* W_ih1 = (const float*)d_in[11];
  const float* W_hh1 = (const float*)d_in[12];
  const float* b_ih1 = (const float*)d_in[13];
  const float* b_hh1 = (const float*)d_in[14];
  const float* W_fc  = (const float*)d_in[15];
  const float* b_fc  = (const float*)d_in[16];

  char* ws = (char*)d_ws;
  size_t off = 0;
  float* he  = (float*)(ws + off); off += 256u * 1024 * 4;          // 1 MB
  float* a_s = (float*)(ws + off); off += 256u * 64 * 4 * 4;        // 256 KB
  float* a_d = (float*)(ws + off); off += 256u * 64 * 4 * 4;        // 256 KB
  bf16*  hb  = (bf16*)(ws + off);  off += 256u * 64 * 1024 * 2;     // 32 MB
  float* seq = (float*)(ws + off); off += 256u * 16384 * 4;         // 16 MB
  float* X0  = (float*)(ws + off); off += 256u * 3072 * 4;          // 3 MB
  float* y0  = (float*)(ws + off); off += 256u * 1024 * 4;          // 1 MB
  float* X1  = (float*)(ws + off); off += 256u * 3072 * 4;          // 3 MB
  float* y1  = (float*)(ws + off); off += 256u * 1024 * 4;          // 1 MB
  float* Cp  = (float*)(ws + off); off += (size_t)8 * 256 * 3072 * 4; // 25.2 MB (split-K partials)

  // 1) he = x_edge @ W_gat[32:, :]   (M=256, N=1024, K=2016, B is [K,N]) SK=8
  mfma_gemm_k<false><<<dim3(8, 2, 8), 256, 0, stream>>>(
      x_edge, W_gat + 32 * 1024, Cp, 256, 1024, 2016, 2016, 1024, 8);
  reduce_k<<<256, 256, 0, stream>>>(Cp, nullptr, he, 256 * 1024, 1024, 8);
  // 2) h = node-proj + he (bf16)
  node_h_k<<<dim3(4, 256), 256, 0, stream>>>(x_node, W_gat, he, hb);
  // 3) attention logits
  as_ad_k<<<4096, 256, 0, stream>>>(hb, att_s, att_d, a_s, a_d);
  // 4) softmax + aggregation + relu -> seq [256, 16384]
  attn_agg_k<<<256, 256, 0, stream>>>(hb, a_s, a_d, b_gat, seq);
  // 5) X0 = seq @ W_ih0^T + b_ih0   (M=256, N=3072, K=16384, B is [N,K]) SK=8
  mfma_gemm_k<true><<<dim3(24, 2, 8), 256, 0, stream>>>(
      seq, W_ih0, Cp, 256, 3072, 16384, 16384, 16384, 64);
  reduce_k<<<768, 256, 0, stream>>>(Cp, b_ih0, X0, 256 * 3072, 3072, 8);
  // 6) GRU layer 0 scan
  for (int s = 0; s < 32; ++s)
    gru_step_k<<<128, 256, 0, stream>>>(X0, W_hh0, b_hh0, y0, s, s == 0 ? 1 : 0);
  // 7) X1 = y0 @ W_ih1^T + b_ih1    (M=256, N=3072, K=1024) SK=4
  mfma_gemm_k<true><<<dim3(24, 2, 4), 256, 0, stream>>>(
      y0, W_ih1, Cp, 256, 3072, 1024, 1024, 1024, 8);
  reduce_k<<<768, 256, 0, stream>>>(Cp, b_ih1, X1, 256 * 3072, 3072, 4);
  // 8) GRU layer 1 scan
  for (int s = 0; s < 32; ++s)
    gru_step_k<<<128, 256, 0, stream>>>(X1, W_hh1, b_hh1, y1, s, s == 0 ? 1 : 0);
  // 9) out = y1[:, 31] @ W_fc + b_fc
  fc_k<<<32, 256, 0, stream>>>(y1, W_fc, b_fc, (float*)d_out);
}